// Round 1
// baseline (1963.274 us; speedup 1.0000x reference)
//
#include <hip/hip_runtime.h>

#define NSLOTS 2048
#define DIM    512
#define BM     32

typedef __bf16 bf16x8 __attribute__((ext_vector_type(8)));
typedef float  f32x4  __attribute__((ext_vector_type(4)));
typedef unsigned short us4 __attribute__((ext_vector_type(4)));

__device__ __forceinline__ unsigned short f2bf(float f) {
    unsigned u = __builtin_bit_cast(unsigned, f);
    u = (u + 0x7FFFu + ((u >> 16) & 1u)) >> 16;   // RNE
    return (unsigned short)u;
}

// Normalize memory rows -> memN bf16 [2048][512]; transpose raw memory -> memT bf16 [512][2048]
__global__ __launch_bounds__(64) void prep_kernel(const float* __restrict__ mem,
                                                  unsigned short* __restrict__ memN,
                                                  unsigned short* __restrict__ memT) {
    const int n = blockIdx.x;       // slot
    const int lane = threadIdx.x;   // 0..63
    const float4* row = (const float4*)(mem + (size_t)n * DIM);
    float4 v0 = row[lane];
    float4 v1 = row[lane + 64];
    float s = v0.x*v0.x + v0.y*v0.y + v0.z*v0.z + v0.w*v0.w
            + v1.x*v1.x + v1.y*v1.y + v1.z*v1.z + v1.w*v1.w;
    #pragma unroll
    for (int off = 1; off < 64; off <<= 1) s += __shfl_xor(s, off);
    const float rn = 1.0f / fmaxf(sqrtf(s), 1e-12f);
    us4 p0, p1;
    p0.x = f2bf(v0.x * rn); p0.y = f2bf(v0.y * rn); p0.z = f2bf(v0.z * rn); p0.w = f2bf(v0.w * rn);
    p1.x = f2bf(v1.x * rn); p1.y = f2bf(v1.y * rn); p1.z = f2bf(v1.z * rn); p1.w = f2bf(v1.w * rn);
    *(us4*)(memN + (size_t)n * DIM + lane*4)       = p0;
    *(us4*)(memN + (size_t)n * DIM + 256 + lane*4) = p1;
    const float vv[8] = {v0.x, v0.y, v0.z, v0.w, v1.x, v1.y, v1.z, v1.w};
    #pragma unroll
    for (int e = 0; e < 8; ++e) {
        const int d = (e < 4) ? (lane*4 + e) : (256 + lane*4 + (e - 4));
        memT[(size_t)d * NSLOTS + n] = f2bf(vv[e]);   // raw (unnormalized) memory, transposed
    }
}

// One WG = 8 waves = 32 z-rows. Wave w owns slot-chunk [w*256, w*256+256).
__global__ __launch_bounds__(512) void fused_kernel(
    const float* __restrict__ z,
    const unsigned short* __restrict__ memN,
    const unsigned short* __restrict__ memT,
    float* __restrict__ zhat,
    float* __restrict__ attn)
{
    union ShU {
        unsigned short zn[BM][DIM];        // 32 KB, phase 0/1 (XOR-swizzled rows)
        unsigned short pbuf[2][BM][256];   // 2x16 KB, phase 2 (XOR-swizzled rows)
    };
    __shared__ ShU sh;
    __shared__ float wsums[8][BM];
    __shared__ float rsum[BM];

    const int tid  = threadIdx.x;
    const int wid  = tid >> 6;
    const int lane = tid & 63;
    const int l16  = lane & 15;
    const int l4   = lane >> 4;
    const size_t rowbase = (size_t)blockIdx.x * BM;

    // ---- phase 0: load z block, L2-normalize rows, store bf16 to swizzled LDS ----
    {
        const int r   = tid >> 4;    // 0..31 (row)
        const int c16 = tid & 15;
        const float4* zr = (const float4*)(z + (rowbase + r) * DIM);
        float4 v[8];
        float s = 0.f;
        #pragma unroll
        for (int j = 0; j < 8; ++j) {
            v[j] = zr[c16 + j*16];
            s += v[j].x*v[j].x + v[j].y*v[j].y + v[j].z*v[j].z + v[j].w*v[j].w;
        }
        #pragma unroll
        for (int off = 1; off < 16; off <<= 1) s += __shfl_xor(s, off);
        const float rn = 1.0f / fmaxf(sqrtf(s), 1e-12f);
        char* znb = (char*)&sh.zn[r][0];
        #pragma unroll
        for (int j = 0; j < 8; ++j) {
            us4 p;
            p.x = f2bf(v[j].x * rn); p.y = f2bf(v[j].y * rn);
            p.z = f2bf(v[j].z * rn); p.w = f2bf(v[j].w * rn);
            const int byteoff = ((c16*4 + j*64) * 2) ^ ((r & 7) << 4);
            *(us4*)(znb + byteoff) = p;
        }
    }
    __syncthreads();

    // ---- phase 1: GEMM1  S[32][256] = zn @ memN^T (wave's chunk), K=512 ----
    const f32x4 zeroV = {0.f, 0.f, 0.f, 0.f};
    f32x4 acc[2][16];
    #pragma unroll
    for (int mt = 0; mt < 2; ++mt)
        #pragma unroll
        for (int nt = 0; nt < 16; ++nt) acc[mt][nt] = zeroV;
    {
        const unsigned short* bbase = memN + (size_t)(wid*256 + l16) * DIM + l4*8;
        const char* znb = (const char*)&sh.zn[0][0];
        for (int kk = 0; kk < 16; ++kk) {
            bf16x8 a[2];
            #pragma unroll
            for (int mt = 0; mt < 2; ++mt) {
                const int r = mt*16 + l16;
                const int byteoff = r*1024 + ((kk*64 + l4*16) ^ ((r & 7) << 4));
                a[mt] = *(const bf16x8*)(znb + byteoff);
            }
            #pragma unroll
            for (int nt = 0; nt < 16; ++nt) {
                bf16x8 b = *(const bf16x8*)(bbase + (size_t)nt*16*DIM + kk*32);
                acc[0][nt] = __builtin_amdgcn_mfma_f32_16x16x32_bf16(a[0], b, acc[0][nt], 0, 0, 0);
                acc[1][nt] = __builtin_amdgcn_mfma_f32_16x16x32_bf16(a[1], b, acc[1][nt], 0, 0, 0);
            }
        }
    }

    // ---- exp (no max-sub needed: |logit| <= ~1) + row sums ----
    float psum[8];
    #pragma unroll
    for (int i = 0; i < 8; ++i) psum[i] = 0.f;
    #pragma unroll
    for (int mt = 0; mt < 2; ++mt)
        #pragma unroll
        for (int nt = 0; nt < 16; ++nt)
            #pragma unroll
            for (int r = 0; r < 4; ++r) {
                const float e = __expf(acc[mt][nt][r]);
                acc[mt][nt][r] = e;
                psum[mt*4 + r] += e;
            }
    #pragma unroll
    for (int i = 0; i < 8; ++i)
        #pragma unroll
        for (int off = 1; off < 16; off <<= 1) psum[i] += __shfl_xor(psum[i], off);
    if (l16 == 0) {
        #pragma unroll
        for (int mt = 0; mt < 2; ++mt)
            #pragma unroll
            for (int r = 0; r < 4; ++r)
                wsums[wid][mt*16 + l4*4 + r] = psum[mt*4 + r];
    }
    __syncthreads();
    if (tid < BM) {
        float t = 0.f;
        #pragma unroll
        for (int w = 0; w < 8; ++w) t += wsums[w][tid];
        rsum[tid] = 1.0f / t;
    }
    __syncthreads();

    float rs[2][4];
    #pragma unroll
    for (int mt = 0; mt < 2; ++mt)
        #pragma unroll
        for (int r = 0; r < 4; ++r) rs[mt][r] = rsum[mt*16 + l4*4 + r];

    // ---- attn output (fp32, from registers; all waves in parallel) ----
    {
        float* abase = attn + rowbase * NSLOTS + wid*256;
        #pragma unroll
        for (int mt = 0; mt < 2; ++mt)
            #pragma unroll
            for (int r = 0; r < 4; ++r) {
                float* ar = abase + (size_t)(mt*16 + l4*4 + r) * NSLOTS;
                #pragma unroll
                for (int nt = 0; nt < 16; ++nt)
                    ar[nt*16 + l16] = acc[mt][nt][r] * rs[mt][r];
            }
    }

    // ---- phase 2: GEMM2  z_hat = P @ memory, K=2048 chunked by owner wave ----
    f32x4 acc2[2][4];
    #pragma unroll
    for (int mt = 0; mt < 2; ++mt)
        #pragma unroll
        for (int dt = 0; dt < 4; ++dt) acc2[mt][dt] = zeroV;

    auto dump = [&](int buf) {   // owner wave dumps its exp(S) chunk -> swizzled LDS bf16
        char* pb = (char*)&sh.pbuf[buf][0][0];
        #pragma unroll
        for (int mt = 0; mt < 2; ++mt)
            #pragma unroll
            for (int r = 0; r < 4; ++r) {
                const int row = mt*16 + l4*4 + r;
                char* pr = pb + row*512;
                #pragma unroll
                for (int nt = 0; nt < 16; ++nt) {
                    const int byteoff = ((nt*16 + l16)*2) ^ ((row & 7) << 4);
                    *(unsigned short*)(pr + byteoff) = f2bf(acc[mt][nt][r]);
                }
            }
    };

    if (wid == 0) dump(0);
    __syncthreads();

    for (int c = 0; c < 8; ++c) {
        if (wid == c + 1) dump((c + 1) & 1);             // prefetch next chunk's P
        const unsigned short* b2base = memT + (size_t)(wid*64 + l16) * NSLOTS + c*256 + l4*8;
        const char* pb = (const char*)&sh.pbuf[c & 1][0][0];
        for (int kk = 0; kk < 8; ++kk) {
            bf16x8 a[2];
            #pragma unroll
            for (int mt = 0; mt < 2; ++mt) {
                const int row = mt*16 + l16;
                const int byteoff = row*512 + ((kk*64 + l4*16) ^ ((row & 7) << 4));
                a[mt] = *(const bf16x8*)(pb + byteoff);
            }
            #pragma unroll
            for (int dt = 0; dt < 4; ++dt) {
                bf16x8 b = *(const bf16x8*)(b2base + (size_t)dt*16*NSLOTS + kk*32);
                acc2[0][dt] = __builtin_amdgcn_mfma_f32_16x16x32_bf16(a[0], b, acc2[0][dt], 0, 0, 0);
                acc2[1][dt] = __builtin_amdgcn_mfma_f32_16x16x32_bf16(a[1], b, acc2[1][dt], 0, 0, 0);
            }
        }
        __syncthreads();
    }

    // ---- epilogue: z_hat = acc2 * (1/sum) ----
    {
        float* zbase = zhat + rowbase * DIM + wid*64;
        #pragma unroll
        for (int mt = 0; mt < 2; ++mt)
            #pragma unroll
            for (int r = 0; r < 4; ++r) {
                float* zr = zbase + (size_t)(mt*16 + l4*4 + r) * DIM;
                #pragma unroll
                for (int dt = 0; dt < 4; ++dt)
                    zr[dt*16 + l16] = acc2[mt][dt][r] * rs[mt][r];
            }
    }
}

extern "C" void kernel_launch(void* const* d_in, const int* in_sizes, int n_in,
                              void* d_out, int out_size, void* d_ws, size_t ws_size,
                              hipStream_t stream) {
    const float* zin = (const float*)d_in[0];
    const float* mem = (const float*)d_in[1];
    const int B = in_sizes[0] / DIM;                 // 65536
    unsigned short* memN = (unsigned short*)d_ws;    // 2 MB
    unsigned short* memT = memN + (size_t)NSLOTS * DIM;  // 2 MB
    float* zhat = (float*)d_out;
    float* attn = zhat + (size_t)B * DIM;
    prep_kernel<<<NSLOTS, 64, 0, stream>>>(mem, memN, memT);
    fused_kernel<<<B / BM, 512, 0, stream>>>(zin, memN, memT, zhat, attn);
}

// Round 2
// 1924.506 us; speedup vs baseline: 1.0201x; 1.0201x over previous
//
#include <hip/hip_runtime.h>

#define NSLOTS 2048
#define DIM    512
#define BM     32

typedef __bf16 bf16x8 __attribute__((ext_vector_type(8)));
typedef float  f32x4  __attribute__((ext_vector_type(4)));
typedef unsigned short us4 __attribute__((ext_vector_type(4)));
typedef unsigned short us8 __attribute__((ext_vector_type(8)));

__device__ __forceinline__ unsigned short f2bf(float f) {
    unsigned u = __builtin_bit_cast(unsigned, f);
    u = (u + 0x7FFFu + ((u >> 16) & 1u)) >> 16;   // RNE
    return (unsigned short)u;
}
__device__ __forceinline__ float bf2f(unsigned short u) {
    unsigned v = ((unsigned)u) << 16;
    return __builtin_bit_cast(float, v);
}

// prep: 64 WGs x 512 thr; WG handles 32 slots. memN = normalized rows (bf16),
// memT = raw memory transposed [512][2048] bf16, written in 64B segments via LDS.
__global__ __launch_bounds__(512) void prep_kernel(const float* __restrict__ mem,
                                                   unsigned short* __restrict__ memN,
                                                   unsigned short* __restrict__ memT) {
    __shared__ unsigned short T[32][516];
    const int tid = threadIdx.x;
    const int sl  = tid >> 4;        // local slot 0..31
    const int c16 = tid & 15;        // 16 threads per slot, 32 floats each
    const int n   = blockIdx.x * 32 + sl;
    const f32x4* row = (const f32x4*)(mem + (size_t)n * DIM);
    f32x4 v[8];
    float s = 0.f;
    #pragma unroll
    for (int j = 0; j < 8; ++j) {
        v[j] = row[c16*8 + j];
        s += v[j][0]*v[j][0] + v[j][1]*v[j][1] + v[j][2]*v[j][2] + v[j][3]*v[j][3];
    }
    #pragma unroll
    for (int off = 1; off < 16; off <<= 1) s += __shfl_xor(s, off);
    const float rn = 1.0f / fmaxf(sqrtf(s), 1e-12f);
    #pragma unroll
    for (int j = 0; j < 8; ++j) {
        us4 p, q;
        #pragma unroll
        for (int e = 0; e < 4; ++e) { p[e] = f2bf(v[j][e] * rn); q[e] = f2bf(v[j][e]); }
        *(us4*)(memN + (size_t)n * DIM + c16*32 + j*4) = p;
        *(us4*)(&T[sl][c16*32 + j*4]) = q;
    }
    __syncthreads();
    const int c4 = tid & 3;
    #pragma unroll
    for (int i = 0; i < 4; ++i) {
        const int d = i*128 + (tid >> 2);
        us8 g;
        #pragma unroll
        for (int j = 0; j < 8; ++j) g[j] = T[c4*8 + j][d];
        *(us8*)(memT + (size_t)d * NSLOTS + blockIdx.x*32 + c4*8) = g;
    }
}

// One WG = 8 waves = 32 z-rows. Wave w owns slot-chunk [w*256, w*256+256).
__global__ __launch_bounds__(512) void fused_kernel(
    const float* __restrict__ z,
    const unsigned short* __restrict__ memN,
    const unsigned short* __restrict__ memT,
    float* __restrict__ zhat,
    float* __restrict__ attn)
{
    union ShU {
        unsigned short zn[BM][DIM];        // 32 KB, phase 0/1 (XOR-swizzled rows)
        unsigned short pbuf[2][BM][256];   // 2x16 KB, phase 2 (XOR-swizzled rows)
    };
    __shared__ ShU sh;
    __shared__ float wsums[8][BM];
    __shared__ float rsum[BM];

    const int tid  = threadIdx.x;
    const int wid  = tid >> 6;
    const int lane = tid & 63;
    const int l16  = lane & 15;
    const int l4   = lane >> 4;
    const size_t rowbase = (size_t)blockIdx.x * BM;

    // ---- phase 0: load z block (NT), L2-normalize rows, store bf16 to swizzled LDS ----
    {
        const int r   = tid >> 4;    // 0..31 (row)
        const int c16 = tid & 15;
        const f32x4* zr = (const f32x4*)(z + (rowbase + r) * DIM);
        f32x4 v[8];
        float s = 0.f;
        #pragma unroll
        for (int j = 0; j < 8; ++j) {
            v[j] = __builtin_nontemporal_load(zr + c16 + j*16);
            s += v[j][0]*v[j][0] + v[j][1]*v[j][1] + v[j][2]*v[j][2] + v[j][3]*v[j][3];
        }
        #pragma unroll
        for (int off = 1; off < 16; off <<= 1) s += __shfl_xor(s, off);
        const float rn = 1.0f / fmaxf(sqrtf(s), 1e-12f);
        char* znb = (char*)&sh.zn[r][0];
        #pragma unroll
        for (int j = 0; j < 8; ++j) {
            us4 p;
            #pragma unroll
            for (int e = 0; e < 4; ++e) p[e] = f2bf(v[j][e] * rn);
            const int byteoff = ((c16*4 + j*64) * 2) ^ ((r & 7) << 4);
            *(us4*)(znb + byteoff) = p;
        }
    }
    __syncthreads();

    // ---- phase 1: GEMM1  S[32][256] = zn @ memN^T (wave's chunk), K=512 ----
    const f32x4 zeroV = {0.f, 0.f, 0.f, 0.f};
    f32x4 acc[2][16];
    #pragma unroll
    for (int mt = 0; mt < 2; ++mt)
        #pragma unroll
        for (int nt = 0; nt < 16; ++nt) acc[mt][nt] = zeroV;
    {
        const unsigned short* bbase = memN + (size_t)(wid*256 + l16) * DIM + l4*8;
        const char* znb = (const char*)&sh.zn[0][0];
        for (int kk = 0; kk < 16; ++kk) {
            bf16x8 a[2];
            #pragma unroll
            for (int mt = 0; mt < 2; ++mt) {
                const int r = mt*16 + l16;
                const int byteoff = r*1024 + ((kk*64 + l4*16) ^ ((r & 7) << 4));
                a[mt] = *(const bf16x8*)(znb + byteoff);
            }
            #pragma unroll
            for (int nt = 0; nt < 16; ++nt) {
                bf16x8 b = *(const bf16x8*)(bbase + (size_t)nt*16*DIM + kk*32);
                acc[0][nt] = __builtin_amdgcn_mfma_f32_16x16x32_bf16(a[0], b, acc[0][nt], 0, 0, 0);
                acc[1][nt] = __builtin_amdgcn_mfma_f32_16x16x32_bf16(a[1], b, acc[1][nt], 0, 0, 0);
            }
        }
    }

    // ---- exp (no max-sub needed: |logit| <= ~1) + row sums ----
    float psum[8];
    #pragma unroll
    for (int i = 0; i < 8; ++i) psum[i] = 0.f;
    #pragma unroll
    for (int mt = 0; mt < 2; ++mt)
        #pragma unroll
        for (int nt = 0; nt < 16; ++nt)
            #pragma unroll
            for (int r = 0; r < 4; ++r) {
                const float e = __expf(acc[mt][nt][r]);
                acc[mt][nt][r] = e;
                psum[mt*4 + r] += e;
            }
    #pragma unroll
    for (int i = 0; i < 8; ++i)
        #pragma unroll
        for (int off = 1; off < 16; off <<= 1) psum[i] += __shfl_xor(psum[i], off);
    if (l16 == 0) {
        #pragma unroll
        for (int mt = 0; mt < 2; ++mt)
            #pragma unroll
            for (int r = 0; r < 4; ++r)
                wsums[wid][mt*16 + l4*4 + r] = psum[mt*4 + r];
    }
    __syncthreads();
    if (tid < BM) {
        float t = 0.f;
        #pragma unroll
        for (int w = 0; w < 8; ++w) t += wsums[w][tid];
        rsum[tid] = 1.0f / t;
    }
    __syncthreads();

    float rs[2][4];
    #pragma unroll
    for (int mt = 0; mt < 2; ++mt)
        #pragma unroll
        for (int r = 0; r < 4; ++r) rs[mt][r] = rsum[mt*16 + l4*4 + r];
    const float sc_attn = rsum[tid >> 4];   // scale for the attn-write row this thread owns

    // ---- phase 2: GEMM2 z_hat = P @ memory (K=2048 chunked) + coalesced attn writes ----
    f32x4 acc2[2][4];
    #pragma unroll
    for (int mt = 0; mt < 2; ++mt)
        #pragma unroll
        for (int dt = 0; dt < 4; ++dt) acc2[mt][dt] = zeroV;

    auto dump = [&](int buf) {   // owner wave dumps its exp(S) chunk -> swizzled LDS bf16
        char* pb = (char*)&sh.pbuf[buf][0][0];
        #pragma unroll
        for (int mt = 0; mt < 2; ++mt)
            #pragma unroll
            for (int r = 0; r < 4; ++r) {
                const int row = mt*16 + l4*4 + r;
                char* pr = pb + row*512;
                #pragma unroll
                for (int nt = 0; nt < 16; ++nt) {
                    const int byteoff = ((nt*16 + l16)*2) ^ ((row & 7) << 4);
                    *(unsigned short*)(pr + byteoff) = f2bf(acc[mt][nt][r]);
                }
            }
    };

    if (wid == 0) dump(0);
    __syncthreads();

    // permuted dims: B-tile dt of this wave covers global dim (wid*64 + l16*4 + dt)
    const unsigned short* b2base = memT + (size_t)(wid*64 + l16*4) * NSLOTS + l4*8;

    for (int c = 0; c < 8; ++c) {
        if (wid == c + 1) dump((c + 1) & 1);             // prefetch next chunk's P

        // ---- coalesced attn write for chunk c (all 512 threads) ----
        {
            const int r   = tid >> 4;
            const int c16 = tid & 15;
            const char* pb = (const char*)&sh.pbuf[c & 1][0][0];
            float* abase = attn + (rowbase + r) * (size_t)NSLOTS + c*256;
            #pragma unroll
            for (int q = 0; q < 4; ++q) {
                const int byteoff = r*512 + ((q*128 + c16*8) ^ ((r & 7) << 4));
                us4 pv = *(const us4*)(pb + byteoff);
                f32x4 o;
                #pragma unroll
                for (int e = 0; e < 4; ++e) o[e] = bf2f(pv[e]) * sc_attn;
                __builtin_nontemporal_store(o, (f32x4*)(abase + q*64 + c16*4));
            }
        }

        // ---- GEMM2 MFMA on chunk c ----
        {
            const char* pb = (const char*)&sh.pbuf[c & 1][0][0];
            const unsigned short* b2 = b2base + (size_t)c * 256;
            for (int kk = 0; kk < 8; ++kk) {
                bf16x8 a[2];
                #pragma unroll
                for (int mt = 0; mt < 2; ++mt) {
                    const int row = mt*16 + l16;
                    const int byteoff = row*512 + ((kk*64 + l4*16) ^ ((row & 7) << 4));
                    a[mt] = *(const bf16x8*)(pb + byteoff);
                }
                #pragma unroll
                for (int dt = 0; dt < 4; ++dt) {
                    bf16x8 b = *(const bf16x8*)(b2 + (size_t)dt*NSLOTS + kk*32);
                    acc2[0][dt] = __builtin_amdgcn_mfma_f32_16x16x32_bf16(a[0], b, acc2[0][dt], 0, 0, 0);
                    acc2[1][dt] = __builtin_amdgcn_mfma_f32_16x16x32_bf16(a[1], b, acc2[1][dt], 0, 0, 0);
                }
            }
        }
        __syncthreads();
    }

    // ---- epilogue: z_hat = acc2 * (1/sum), float4 contiguous (dims l16*4..l16*4+3) ----
    {
        float* zbase = zhat + rowbase * DIM + wid*64;
        #pragma unroll
        for (int mt = 0; mt < 2; ++mt)
            #pragma unroll
            for (int r = 0; r < 4; ++r) {
                const int row = mt*16 + l4*4 + r;
                f32x4 o;
                #pragma unroll
                for (int dt = 0; dt < 4; ++dt) o[dt] = acc2[mt][dt][r] * rs[mt][r];
                __builtin_nontemporal_store(o, (f32x4*)(zbase + (size_t)row * DIM + l16*4));
            }
    }
}

extern "C" void kernel_launch(void* const* d_in, const int* in_sizes, int n_in,
                              void* d_out, int out_size, void* d_ws, size_t ws_size,
                              hipStream_t stream) {
    const float* zin = (const float*)d_in[0];
    const float* mem = (const float*)d_in[1];
    const int B = in_sizes[0] / DIM;                 // 65536
    unsigned short* memN = (unsigned short*)d_ws;    // 2 MB
    unsigned short* memT = memN + (size_t)NSLOTS * DIM;  // 2 MB
    float* zhat = (float*)d_out;
    float* attn = zhat + (size_t)B * DIM;
    prep_kernel<<<NSLOTS / 32, 512, 0, stream>>>(mem, memN, memT);
    fused_kernel<<<B / BM, 512, 0, stream>>>(zin, memN, memT, zhat, attn);
}